// Round 1
// baseline (1289.208 us; speedup 1.0000x reference)
//
#include <hip/hip_runtime.h>

#define DEPTH 18
#define EMB 128
#define HID 256
#define VAL 32
#define N_LEAVES (1 << DEPTH)
#define LEAF_START (N_LEAVES - 1)

typedef _Float16 half8 __attribute__((ext_vector_type(8)));
typedef _Float16 half4 __attribute__((ext_vector_type(4)));
typedef float f32x4 __attribute__((ext_vector_type(4)));

__device__ __forceinline__ float lrelu(float x) { return x > 0.f ? x : 0.01f * x; }

// ---------------------------------------------------------------------------
// Prep: swizzle W1 (256x256) and W2 (256x128) into fp16 MFMA A-fragment order
// for the TRANSPOSED GEMMs (A = W^T, m = output col, k = contraction dim).
// Now emits BOTH hi (f16 rounding of W) and lo (f16 of residual W - hi) frags:
// the lo arrays feed the split-precision tail so the last 7 levels stay at
// effectively-fp32 accuracy while using MFMA.
// Frag lane layout (16x16x32): lane holds A[m = lane&15][k = (lane>>4)*8 + jj].
// ---------------------------------------------------------------------------
__global__ __launch_bounds__(256) void prep_weights(
    const float* __restrict__ W1, const float* __restrict__ W2,
    _Float16* __restrict__ W1f, _Float16* __restrict__ W2f,
    _Float16* __restrict__ W1l, _Float16* __restrict__ W2l)
{
    const int gid = blockIdx.x * 256 + threadIdx.x;   // 12288 total (8192 + 4096)
    const int lane = gid & 63;
    const int nn = lane & 15, q = lane >> 4;
    if (gid < 8192) {
        const int f = gid >> 6, kb = f >> 4, jt = f & 15;
        half8 vh, vl;
#pragma unroll
        for (int jj = 0; jj < 8; ++jj) {
            float x = W1[(kb * 32 + q * 8 + jj) * HID + jt * 16 + nn];
            _Float16 h = (_Float16)x;
            vh[jj] = h;
            vl[jj] = (_Float16)(x - (float)h);
        }
        *((half8*)W1f + gid) = vh;
        *((half8*)W1l + gid) = vl;
    } else {
        const int g = gid - 8192;
        const int f = g >> 6, kb = f >> 3, ct = f & 7;
        half8 vh, vl;
#pragma unroll
        for (int jj = 0; jj < 8; ++jj) {
            float x = W2[(kb * 32 + q * 8 + jj) * EMB + ct * 16 + nn];
            _Float16 h = (_Float16)x;
            vh[jj] = h;
            vl[jj] = (_Float16)(x - (float)h);
        }
        *((half8*)W2f + g) = vh;
        *((half8*)W2l + g) = vl;
    }
}

// ---------------------------------------------------------------------------
// Leaf embedding: lrelu(leaf_values @ We + be) -> embs[LEAF_START..] (fp32)
// ---------------------------------------------------------------------------
__global__ __launch_bounds__(256) void leaf_embed(
    const float* __restrict__ lv, const float* __restrict__ We,
    const float* __restrict__ be, float* __restrict__ embs)
{
    __shared__ float lvs[16][VAL];
    const int j = threadIdx.x & 127;
    const int h = threadIdx.x >> 7;

    float w[VAL];
#pragma unroll
    for (int k = 0; k < VAL; ++k) w[k] = We[k * EMB + j];
    const float bj = be[j];

    const int leaf0 = blockIdx.x * 16;
    {
        const float* src = lv + (size_t)leaf0 * VAL;
        ((float*)lvs)[threadIdx.x]       = src[threadIdx.x];
        ((float*)lvs)[threadIdx.x + 256] = src[threadIdx.x + 256];
    }
    __syncthreads();

#pragma unroll
    for (int it = 0; it < 8; ++it) {
        const int ll = it * 2 + h;
        float acc = bj;
#pragma unroll
        for (int k4 = 0; k4 < VAL / 4; ++k4) {
            float4 x4 = *(const float4*)&lvs[ll][k4 * 4];
            acc += x4.x * w[k4*4] + x4.y * w[k4*4+1] + x4.z * w[k4*4+2] + x4.w * w[k4*4+3];
        }
        embs[(size_t)(LEAF_START + leaf0 + ll) * EMB + j] = lrelu(acc);
    }
}

// ---------------------------------------------------------------------------
// One tree level via fp16 MFMA, transposed dataflow. n >= 64, n % 64 == 0.
//   GEMM1': H^T = W1^T @ X^T   (D1[hid][row])
//   GEMM2': O^T = W2^T @ H^T   (D2[col][row])
// Block = 4 waves, each wave owns 16 rows (parents). X read fp32 directly from
// embs (children are the contiguous node range starting at 2*p0+1), converted
// to f16 in-register. H round-trips through a per-wave 16x264 f16 LDS tile
// (b64 writes / b128 reads, conflict-free with the +8 pad). Output written
// fp32 straight to embs.
// ---------------------------------------------------------------------------
__global__ __launch_bounds__(256) void level_mfma(
    const _Float16* __restrict__ W1f, const _Float16* __restrict__ W2f,
    const float* __restrict__ b1, const float* __restrict__ b2,
    float* __restrict__ embs, int p0)
{
    __shared__ _Float16 Hs[4][16][264];   // 33792 B
    const int tid  = threadIdx.x;
    const int w    = tid >> 6;
    const int lane = tid & 63;
    const int n    = lane & 15;   // row within wave strip / operand 16-index
    const int q    = lane >> 4;   // quad
    const int i0   = blockIdx.x * 64 + w * 16;

    // X row pointer for this lane (fp32, k-contiguous)
    const float* Xrow = embs + (size_t)(2 * p0 + 1) * EMB + (size_t)(i0 + n) * 256 + q * 8;

    // ---- GEMM1': accumulate H^T, bias-initialized ----
    f32x4 d1[16];
#pragma unroll
    for (int jt = 0; jt < 16; ++jt)
        d1[jt] = *(const f32x4*)(b1 + jt * 16 + q * 4);

#pragma unroll
    for (int kb = 0; kb < 8; ++kb) {
        f32x4 u = *(const f32x4*)(Xrow + kb * 32);
        f32x4 v = *(const f32x4*)(Xrow + kb * 32 + 4);
        half8 bfrag;
        bfrag[0] = (_Float16)u[0]; bfrag[1] = (_Float16)u[1];
        bfrag[2] = (_Float16)u[2]; bfrag[3] = (_Float16)u[3];
        bfrag[4] = (_Float16)v[0]; bfrag[5] = (_Float16)v[1];
        bfrag[6] = (_Float16)v[2]; bfrag[7] = (_Float16)v[3];
        const half8* wf = (const half8*)W1f + (size_t)kb * 16 * 64 + lane;
#pragma unroll
        for (int jt = 0; jt < 16; ++jt) {
            half8 a = wf[jt * 64];
            d1[jt] = __builtin_amdgcn_mfma_f32_16x16x32_f16(a, bfrag, d1[jt], 0, 0, 0);
        }
    }

    // ---- epilogue 1: lrelu, f16, store H^T tile to LDS (row-major H[n][hid]) ----
    _Float16* hrow = &Hs[w][n][0];
#pragma unroll
    for (int jt = 0; jt < 16; ++jt) {
        half4 h;
#pragma unroll
        for (int r = 0; r < 4; ++r) { float x = d1[jt][r]; h[r] = (_Float16)(x > 0.f ? x : 0.01f * x); }
        *(half4*)(hrow + jt * 16 + q * 4) = h;   // intra-wave only; no barrier needed
    }

    // ---- GEMM2': O^T = W2^T @ H^T ----
    f32x4 d2[8];
#pragma unroll
    for (int ct = 0; ct < 8; ++ct)
        d2[ct] = *(const f32x4*)(b2 + ct * 16 + q * 4);

#pragma unroll
    for (int kb = 0; kb < 8; ++kb) {
        half8 bfrag = *(const half8*)(hrow + kb * 32 + q * 8);
        const half8* wf = (const half8*)W2f + (size_t)kb * 8 * 64 + lane;
#pragma unroll
        for (int ct = 0; ct < 8; ++ct) {
            half8 a = wf[ct * 64];
            d2[ct] = __builtin_amdgcn_mfma_f32_16x16x32_f16(a, bfrag, d2[ct], 0, 0, 0);
        }
    }

    // ---- epilogue 2: lrelu, store fp32 rows to embs ----
    float* orow = embs + (size_t)(p0 + i0 + n) * EMB + q * 4;
#pragma unroll
    for (int ct = 0; ct < 8; ++ct) {
        f32x4 o;
#pragma unroll
        for (int r = 0; r < 4; ++r) { float x = d2[ct][r]; o[r] = x > 0.f ? x : 0.01f * x; }
        *(f32x4*)(orow + ct * 16) = o;
    }
}

// ---------------------------------------------------------------------------
// Levels 6..0 (127 nodes) fused in ONE 4-wave block, split-precision f16 MFMA
// (acc += xh*wh + xl*wh + xh*wl -> ~fp32 accuracy). Level 6 reads X from
// global (level-7 output); afterwards activations ping-pong between fp32 LDS
// buffers Xa/Xb (rows padded to 140 floats -> <=2-way bank aliasing on the
// strided b128 reads). H stays fp32 in LDS (no f16 rounding in the tail).
// Waves beyond ceil(n/16) idle at the barrier; rows >= n compute garbage that
// is never stored to global and only ever feeds other garbage rows.
// ---------------------------------------------------------------------------
__global__ __launch_bounds__(256) void tail_levels(
    const _Float16* __restrict__ W1f, const _Float16* __restrict__ W1l,
    const _Float16* __restrict__ W2f, const _Float16* __restrict__ W2l,
    const float* __restrict__ b1, const float* __restrict__ b2,
    float* __restrict__ embs)
{
    __shared__ alignas(16) float Hs[4][16][268];   // 68608 B, per-wave private
    __shared__ alignas(16) float Xa[64 * 140];     // 35840 B
    __shared__ alignas(16) float Xb[32 * 140];     // 17920 B  (total ~119.5 KB)

    const int tid  = threadIdx.x;
    const int w    = tid >> 6;
    const int lane = tid & 63;
    const int nl   = lane & 15;
    const int q    = lane >> 4;

#pragma unroll 1
    for (int l = 6; l >= 0; --l) {
        const int p0 = (1 << l) - 1, n = 1 << l;
        const int nw = (n >= 16) ? (n >> 4) : 1;           // active waves (<=4)
        float* outb = (l & 1) ? Xb : Xa;                   // l even -> Xa
        const float* inb = (l & 1) ? Xa : Xb;              // l==6 unused (global)

        if (w < nw) {
            const int row = w * 16 + nl;                   // parent strip row

            // ---- GEMM1': H^T = W1^T @ X^T, bias-initialized, split f16 ----
            f32x4 d1[16];
#pragma unroll
            for (int jt = 0; jt < 16; ++jt)
                d1[jt] = *(const f32x4*)(b1 + jt * 16 + q * 4);

#pragma unroll
            for (int kb = 0; kb < 8; ++kb) {
                f32x4 u, v;
                if (l == 6) {
                    const float* Xrow = embs + (size_t)(2 * p0 + 1) * EMB
                                      + (size_t)row * 256 + kb * 32 + q * 8;
                    u = *(const f32x4*)Xrow;
                    v = *(const f32x4*)(Xrow + 4);
                } else {
                    // X row = concat(child 2*row, child 2*row+1), each 128 f32
                    const float* c = inb + (2 * row + (kb >> 2)) * 140
                                   + (kb & 3) * 32 + q * 8;
                    u = *(const f32x4*)c;
                    v = *(const f32x4*)(c + 4);
                }
                half8 xh, xl;
#pragma unroll
                for (int r = 0; r < 4; ++r) {
                    float a = u[r]; _Float16 h = (_Float16)a;
                    xh[r] = h; xl[r] = (_Float16)(a - (float)h);
                    float b = v[r]; _Float16 g = (_Float16)b;
                    xh[r + 4] = g; xl[r + 4] = (_Float16)(b - (float)g);
                }
                const half8* wh = (const half8*)W1f + (size_t)kb * 16 * 64 + lane;
                const half8* wl = (const half8*)W1l + (size_t)kb * 16 * 64 + lane;
#pragma unroll
                for (int jt = 0; jt < 16; ++jt) {
                    half8 ah = wh[jt * 64];
                    half8 al = wl[jt * 64];
                    d1[jt] = __builtin_amdgcn_mfma_f32_16x16x32_f16(ah, xh, d1[jt], 0, 0, 0);
                    d1[jt] = __builtin_amdgcn_mfma_f32_16x16x32_f16(ah, xl, d1[jt], 0, 0, 0);
                    d1[jt] = __builtin_amdgcn_mfma_f32_16x16x32_f16(al, xh, d1[jt], 0, 0, 0);
                }
            }

            // ---- epilogue 1: lrelu, store H fp32 to per-wave LDS tile ----
            float* hrow = &Hs[w][nl][0];
#pragma unroll
            for (int jt = 0; jt < 16; ++jt) {
                f32x4 h;
#pragma unroll
                for (int r = 0; r < 4; ++r) { float x = d1[jt][r]; h[r] = x > 0.f ? x : 0.01f * x; }
                *(f32x4*)(hrow + jt * 16 + q * 4) = h;     // intra-wave only
            }

            // ---- GEMM2': O^T = W2^T @ H^T, split f16 ----
            f32x4 d2[8];
#pragma unroll
            for (int ct = 0; ct < 8; ++ct)
                d2[ct] = *(const f32x4*)(b2 + ct * 16 + q * 4);

#pragma unroll
            for (int kb = 0; kb < 8; ++kb) {
                f32x4 u = *(const f32x4*)(hrow + kb * 32 + q * 8);
                f32x4 v = *(const f32x4*)(hrow + kb * 32 + q * 8 + 4);
                half8 hh, hl;
#pragma unroll
                for (int r = 0; r < 4; ++r) {
                    float a = u[r]; _Float16 h = (_Float16)a;
                    hh[r] = h; hl[r] = (_Float16)(a - (float)h);
                    float b = v[r]; _Float16 g = (_Float16)b;
                    hh[r + 4] = g; hl[r + 4] = (_Float16)(b - (float)g);
                }
                const half8* wh = (const half8*)W2f + (size_t)kb * 8 * 64 + lane;
                const half8* wl = (const half8*)W2l + (size_t)kb * 8 * 64 + lane;
#pragma unroll
                for (int ct = 0; ct < 8; ++ct) {
                    half8 ah = wh[ct * 64];
                    half8 al = wl[ct * 64];
                    d2[ct] = __builtin_amdgcn_mfma_f32_16x16x32_f16(ah, hh, d2[ct], 0, 0, 0);
                    d2[ct] = __builtin_amdgcn_mfma_f32_16x16x32_f16(ah, hl, d2[ct], 0, 0, 0);
                    d2[ct] = __builtin_amdgcn_mfma_f32_16x16x32_f16(al, hh, d2[ct], 0, 0, 0);
                }
            }

            // ---- epilogue 2: lrelu; LDS out for next level, global for row<n ----
#pragma unroll
            for (int ct = 0; ct < 8; ++ct) {
                f32x4 o;
#pragma unroll
                for (int r = 0; r < 4; ++r) { float x = d2[ct][r]; o[r] = x > 0.f ? x : 0.01f * x; }
                if (l > 0)
                    *(f32x4*)(outb + row * 140 + ct * 16 + q * 4) = o;
                if (row < n)
                    *(f32x4*)(embs + (size_t)(p0 + row) * EMB + ct * 16 + q * 4) = o;
            }
        }
        __syncthreads();   // all 256 threads, every level
    }
}

// ---------------------------------------------------------------------------
extern "C" void kernel_launch(void* const* d_in, const int* in_sizes, int n_in,
                              void* d_out, int out_size, void* d_ws, size_t ws_size,
                              hipStream_t stream)
{
    const float* lv = (const float*)d_in[0];
    const float* We = (const float*)d_in[1];
    const float* be = (const float*)d_in[2];
    const float* W1 = (const float*)d_in[3];
    const float* b1 = (const float*)d_in[4];
    const float* W2 = (const float*)d_in[5];
    const float* b2 = (const float*)d_in[6];
    float* embs = (float*)d_out;

    _Float16* W1f = (_Float16*)d_ws;            // 65536 f16 = 128 KB
    _Float16* W2f = W1f + 65536;                // 32768 f16 =  64 KB
    _Float16* W1l = W2f + 32768;                // 65536 f16 = 128 KB
    _Float16* W2l = W1l + 65536;                // 32768 f16 =  64 KB  (384 KB total)

    prep_weights<<<48, 256, 0, stream>>>(W1, W2, W1f, W2f, W1l, W2l);
    leaf_embed<<<N_LEAVES / 16, 256, 0, stream>>>(lv, We, be, embs);
    for (int l = DEPTH - 1; l >= 7; --l) {
        const int p0 = (1 << l) - 1, n = 1 << l;
        level_mfma<<<n / 64, 256, 0, stream>>>(W1f, W2f, b1, b2, embs, p0);
    }
    tail_levels<<<1, 256, 0, stream>>>(W1f, W1l, W2f, W2l, b1, b2, embs);
}

// Round 2
// 819.861 us; speedup vs baseline: 1.5725x; 1.5725x over previous
//
#include <hip/hip_runtime.h>

#define DEPTH 18
#define EMB 128
#define HID 256
#define VAL 32
#define N_LEAVES (1 << DEPTH)
#define LEAF_START (N_LEAVES - 1)

typedef _Float16 half8 __attribute__((ext_vector_type(8)));
typedef _Float16 half4 __attribute__((ext_vector_type(4)));
typedef float f32x4 __attribute__((ext_vector_type(4)));

__device__ __forceinline__ float lrelu(float x) { return x > 0.f ? x : 0.01f * x; }

// ---------------------------------------------------------------------------
// Prep: swizzle W1 (256x256) and W2 (256x128) into fp16 MFMA A-fragment order
// for the TRANSPOSED GEMMs (A = W^T, m = output col, k = contraction dim).
// Emits BOTH hi (f16 rounding of W) and lo (f16 of residual W - hi) frags:
// the lo arrays feed the split-precision tail so the last 6 levels stay at
// effectively-fp32 accuracy while using MFMA.
// Frag lane layout (16x16x32): lane holds A[m = lane&15][k = (lane>>4)*8 + jj].
// ---------------------------------------------------------------------------
__global__ __launch_bounds__(256) void prep_weights(
    const float* __restrict__ W1, const float* __restrict__ W2,
    _Float16* __restrict__ W1f, _Float16* __restrict__ W2f,
    _Float16* __restrict__ W1l, _Float16* __restrict__ W2l)
{
    const int gid = blockIdx.x * 256 + threadIdx.x;   // 12288 total (8192 + 4096)
    const int lane = gid & 63;
    const int nn = lane & 15, q = lane >> 4;
    if (gid < 8192) {
        const int f = gid >> 6, kb = f >> 4, jt = f & 15;
        half8 vh, vl;
#pragma unroll
        for (int jj = 0; jj < 8; ++jj) {
            float x = W1[(kb * 32 + q * 8 + jj) * HID + jt * 16 + nn];
            _Float16 h = (_Float16)x;
            vh[jj] = h;
            vl[jj] = (_Float16)(x - (float)h);
        }
        *((half8*)W1f + gid) = vh;
        *((half8*)W1l + gid) = vl;
    } else {
        const int g = gid - 8192;
        const int f = g >> 6, kb = f >> 3, ct = f & 7;
        half8 vh, vl;
#pragma unroll
        for (int jj = 0; jj < 8; ++jj) {
            float x = W2[(kb * 32 + q * 8 + jj) * EMB + ct * 16 + nn];
            _Float16 h = (_Float16)x;
            vh[jj] = h;
            vl[jj] = (_Float16)(x - (float)h);
        }
        *((half8*)W2f + g) = vh;
        *((half8*)W2l + g) = vl;
    }
}

// ---------------------------------------------------------------------------
// Leaf embedding: lrelu(leaf_values @ We + be) -> embs[LEAF_START..] (fp32)
// ---------------------------------------------------------------------------
__global__ __launch_bounds__(256) void leaf_embed(
    const float* __restrict__ lv, const float* __restrict__ We,
    const float* __restrict__ be, float* __restrict__ embs)
{
    __shared__ float lvs[16][VAL];
    const int j = threadIdx.x & 127;
    const int h = threadIdx.x >> 7;

    float w[VAL];
#pragma unroll
    for (int k = 0; k < VAL; ++k) w[k] = We[k * EMB + j];
    const float bj = be[j];

    const int leaf0 = blockIdx.x * 16;
    {
        const float* src = lv + (size_t)leaf0 * VAL;
        ((float*)lvs)[threadIdx.x]       = src[threadIdx.x];
        ((float*)lvs)[threadIdx.x + 256] = src[threadIdx.x + 256];
    }
    __syncthreads();

#pragma unroll
    for (int it = 0; it < 8; ++it) {
        const int ll = it * 2 + h;
        float acc = bj;
#pragma unroll
        for (int k4 = 0; k4 < VAL / 4; ++k4) {
            float4 x4 = *(const float4*)&lvs[ll][k4 * 4];
            acc += x4.x * w[k4*4] + x4.y * w[k4*4+1] + x4.z * w[k4*4+2] + x4.w * w[k4*4+3];
        }
        embs[(size_t)(LEAF_START + leaf0 + ll) * EMB + j] = lrelu(acc);
    }
}

// ---------------------------------------------------------------------------
// One tree level via fp16 MFMA, transposed dataflow. n >= 64, n % 64 == 0.
//   GEMM1': H^T = W1^T @ X^T   (D1[hid][row])
//   GEMM2': O^T = W2^T @ H^T   (D2[col][row])
// Block = 4 waves, each wave owns 16 rows (parents). X read fp32 directly from
// embs (children are the contiguous node range starting at 2*p0+1), converted
// to f16 in-register. H round-trips through a per-wave 16x264 f16 LDS tile
// (b64 writes / b128 reads, conflict-free with the +8 pad). Output written
// fp32 straight to embs.
// ---------------------------------------------------------------------------
__global__ __launch_bounds__(256) void level_mfma(
    const _Float16* __restrict__ W1f, const _Float16* __restrict__ W2f,
    const float* __restrict__ b1, const float* __restrict__ b2,
    float* __restrict__ embs, int p0)
{
    __shared__ _Float16 Hs[4][16][264];   // 33792 B
    const int tid  = threadIdx.x;
    const int w    = tid >> 6;
    const int lane = tid & 63;
    const int n    = lane & 15;   // row within wave strip / operand 16-index
    const int q    = lane >> 4;   // quad
    const int i0   = blockIdx.x * 64 + w * 16;

    // X row pointer for this lane (fp32, k-contiguous)
    const float* Xrow = embs + (size_t)(2 * p0 + 1) * EMB + (size_t)(i0 + n) * 256 + q * 8;

    // ---- GEMM1': accumulate H^T, bias-initialized ----
    f32x4 d1[16];
#pragma unroll
    for (int jt = 0; jt < 16; ++jt)
        d1[jt] = *(const f32x4*)(b1 + jt * 16 + q * 4);

#pragma unroll
    for (int kb = 0; kb < 8; ++kb) {
        f32x4 u = *(const f32x4*)(Xrow + kb * 32);
        f32x4 v = *(const f32x4*)(Xrow + kb * 32 + 4);
        half8 bfrag;
        bfrag[0] = (_Float16)u[0]; bfrag[1] = (_Float16)u[1];
        bfrag[2] = (_Float16)u[2]; bfrag[3] = (_Float16)u[3];
        bfrag[4] = (_Float16)v[0]; bfrag[5] = (_Float16)v[1];
        bfrag[6] = (_Float16)v[2]; bfrag[7] = (_Float16)v[3];
        const half8* wf = (const half8*)W1f + (size_t)kb * 16 * 64 + lane;
#pragma unroll
        for (int jt = 0; jt < 16; ++jt) {
            half8 a = wf[jt * 64];
            d1[jt] = __builtin_amdgcn_mfma_f32_16x16x32_f16(a, bfrag, d1[jt], 0, 0, 0);
        }
    }

    // ---- epilogue 1: lrelu, f16, store H^T tile to LDS (row-major H[n][hid]) ----
    _Float16* hrow = &Hs[w][n][0];
#pragma unroll
    for (int jt = 0; jt < 16; ++jt) {
        half4 h;
#pragma unroll
        for (int r = 0; r < 4; ++r) { float x = d1[jt][r]; h[r] = (_Float16)(x > 0.f ? x : 0.01f * x); }
        *(half4*)(hrow + jt * 16 + q * 4) = h;   // intra-wave only; no barrier needed
    }

    // ---- GEMM2': O^T = W2^T @ H^T ----
    f32x4 d2[8];
#pragma unroll
    for (int ct = 0; ct < 8; ++ct)
        d2[ct] = *(const f32x4*)(b2 + ct * 16 + q * 4);

#pragma unroll
    for (int kb = 0; kb < 8; ++kb) {
        half8 bfrag = *(const half8*)(hrow + kb * 32 + q * 8);
        const half8* wf = (const half8*)W2f + (size_t)kb * 8 * 64 + lane;
#pragma unroll
        for (int ct = 0; ct < 8; ++ct) {
            half8 a = wf[ct * 64];
            d2[ct] = __builtin_amdgcn_mfma_f32_16x16x32_f16(a, bfrag, d2[ct], 0, 0, 0);
        }
    }

    // ---- epilogue 2: lrelu, store fp32 rows to embs ----
    float* orow = embs + (size_t)(p0 + i0 + n) * EMB + q * 4;
#pragma unroll
    for (int ct = 0; ct < 8; ++ct) {
        f32x4 o;
#pragma unroll
        for (int r = 0; r < 4; ++r) { float x = d2[ct][r]; o[r] = x > 0.f ? x : 0.01f * x; }
        *(f32x4*)(orow + ct * 16) = o;
    }
}

// ---------------------------------------------------------------------------
// Levels 5..0 (63 nodes) fused in ONE 8-wave block, split-precision f16 MFMA
// (acc += xh*wh + xl*wh + xh*wl -> ~fp32 accuracy, rel err ~2^-22).
//
// Key change vs the failed v1: weights are REGISTER-RESIDENT, loaded ONCE.
//   wave w owns hid tiles {2w, 2w+1} in GEMM1 -> W1 hi+lo = 32 frags = 128 VGPR
//   wave w owns out-col tile {w}  in GEMM2 -> W2 hi+lo = 16 frags =  64 VGPR
// Total 192 persistent VGPR + ~40 transient: fits under the 256 cap
// (__launch_bounds__(512,2)) -> no scratch spills, zero weight re-reads.
//
// Activations ping-pong in LDS as f16 hi/lo pairs:
//   H (cross-wave, barrier-exchanged): [32][264] f16, stride 264 -> 2-way banks
//   O/X (child gather): parity-split [2][16][136] so the stride-2-row child
//   gather (child = 2*nl + hi) is a clean stride-136 read -> 2-way banks.
// Level 5 (n=32) reads X from global embs (level-6 output, contiguous 256).
// Levels <=4 have <=16 real rows -> only strip s=0 computed (the &31 child
// clamp makes strip 1 an exact duplicate anyway). Garbage rows (row>=n) stay
// finite (lrelu + O(1) weights) and never reach global.
// ---------------------------------------------------------------------------
__global__ __launch_bounds__(512, 2) void tail_levels(
    const _Float16* __restrict__ W1f, const _Float16* __restrict__ W1l,
    const _Float16* __restrict__ W2f, const _Float16* __restrict__ W2l,
    const float* __restrict__ b1, const float* __restrict__ b2,
    float* __restrict__ embs)
{
    __shared__ alignas(16) _Float16 Hsh[32][264];      // 16896 B
    __shared__ alignas(16) _Float16 Hsl[32][264];      // 16896 B
    __shared__ alignas(16) _Float16 Obh[2][16][136];   //  8704 B
    __shared__ alignas(16) _Float16 Obl[2][16][136];   //  8704 B   (51.2 KB)

    const int tid  = threadIdx.x;
    const int w    = tid >> 6;        // 0..7
    const int lane = tid & 63;
    const int nl   = lane & 15;
    const int q    = lane >> 4;

    // ---- one-time weight preload into registers (static indexing only) ----
    half8 w1h[8][2], w1l[8][2], w2h[8], w2l[8];
#pragma unroll
    for (int kb = 0; kb < 8; ++kb) {
#pragma unroll
        for (int j = 0; j < 2; ++j) {
            const int f = kb * 16 + (2 * w + j);
            w1h[kb][j] = ((const half8*)W1f)[f * 64 + lane];
            w1l[kb][j] = ((const half8*)W1l)[f * 64 + lane];
        }
        const int g = kb * 8 + w;
        w2h[kb] = ((const half8*)W2f)[g * 64 + lane];
        w2l[kb] = ((const half8*)W2l)[g * 64 + lane];
    }

#pragma unroll 1
    for (int l = 5; l >= 0; --l) {
        const int p0 = (1 << l) - 1, n = 1 << l;
        const int ns = (l == 5) ? 2 : 1;     // strips of 16 rows (uniform)

        // ---- GEMM1': H^T = W1^T @ X^T, bias-init, split f16 ----
        f32x4 d1[2][2];
#pragma unroll
        for (int s = 0; s < 2; ++s)
#pragma unroll
            for (int j = 0; j < 2; ++j)
                d1[s][j] = *(const f32x4*)(b1 + (2 * w + j) * 16 + q * 4);

#pragma unroll
        for (int kb = 0; kb < 8; ++kb) {
            const int k0  = kb * 32 + q * 8;        // 0..255, 8-aligned
            const int hi  = kb >> 2;                // which child half
            const int col = (kb & 3) * 32 + q * 8;  // col within child
#pragma unroll
            for (int s = 0; s < 2; ++s) {
                if (s >= ns) break;
                half8 xh, xl;
                if (l == 5) {
                    const int row = s * 16 + nl;
                    const float* Xr = embs + (size_t)(63 + 2 * row) * EMB + k0;
                    f32x4 u = *(const f32x4*)Xr;
                    f32x4 v = *(const f32x4*)(Xr + 4);
#pragma unroll
                    for (int r = 0; r < 4; ++r) {
                        _Float16 a = (_Float16)u[r];
                        xh[r] = a; xl[r] = (_Float16)(u[r] - (float)a);
                        _Float16 b = (_Float16)v[r];
                        xh[r + 4] = b; xl[r + 4] = (_Float16)(v[r] - (float)b);
                    }
                } else {
                    // child = (2*row + hi) & 31 = 2*nl + hi  (independent of s)
                    xh = *(const half8*)&Obh[hi][nl][col];
                    xl = *(const half8*)&Obl[hi][nl][col];
                }
#pragma unroll
                for (int j = 0; j < 2; ++j) {
                    d1[s][j] = __builtin_amdgcn_mfma_f32_16x16x32_f16(w1h[kb][j], xh, d1[s][j], 0, 0, 0);
                    d1[s][j] = __builtin_amdgcn_mfma_f32_16x16x32_f16(w1h[kb][j], xl, d1[s][j], 0, 0, 0);
                    d1[s][j] = __builtin_amdgcn_mfma_f32_16x16x32_f16(w1l[kb][j], xh, d1[s][j], 0, 0, 0);
                }
            }
        }

        // ---- epilogue 1: lrelu, hi/lo f16, store H to LDS (cross-wave) ----
#pragma unroll
        for (int s = 0; s < 2; ++s) {
            if (s >= ns) break;
            const int row = s * 16 + nl;
#pragma unroll
            for (int j = 0; j < 2; ++j) {
                half4 hh4, hl4;
#pragma unroll
                for (int r = 0; r < 4; ++r) {
                    float x = d1[s][j][r];
                    x = x > 0.f ? x : 0.01f * x;
                    _Float16 a = (_Float16)x;
                    hh4[r] = a; hl4[r] = (_Float16)(x - (float)a);
                }
                const int cf = (2 * w + j) * 16 + q * 4;
                *(half4*)&Hsh[row][cf] = hh4;
                *(half4*)&Hsl[row][cf] = hl4;
            }
        }
        __syncthreads();

        // ---- GEMM2': O^T = W2^T @ H^T, split f16 ----
        f32x4 d2[2];
#pragma unroll
        for (int s = 0; s < 2; ++s)
            d2[s] = *(const f32x4*)(b2 + w * 16 + q * 4);

#pragma unroll
        for (int kb = 0; kb < 8; ++kb) {
#pragma unroll
            for (int s = 0; s < 2; ++s) {
                if (s >= ns) break;
                const int row = s * 16 + nl;
                half8 hh = *(const half8*)&Hsh[row][kb * 32 + q * 8];
                half8 hl = *(const half8*)&Hsl[row][kb * 32 + q * 8];
                d2[s] = __builtin_amdgcn_mfma_f32_16x16x32_f16(w2h[kb], hh, d2[s], 0, 0, 0);
                d2[s] = __builtin_amdgcn_mfma_f32_16x16x32_f16(w2h[kb], hl, d2[s], 0, 0, 0);
                d2[s] = __builtin_amdgcn_mfma_f32_16x16x32_f16(w2l[kb], hh, d2[s], 0, 0, 0);
            }
        }

        // ---- epilogue 2: lrelu; O to parity-split LDS + global for row<n ----
#pragma unroll
        for (int s = 0; s < 2; ++s) {
            if (s >= ns) break;
            const int row = s * 16 + nl;
            f32x4 o;
#pragma unroll
            for (int r = 0; r < 4; ++r) { float x = d2[s][r]; o[r] = x > 0.f ? x : 0.01f * x; }
            half4 oh4, ol4;
#pragma unroll
            for (int r = 0; r < 4; ++r) {
                _Float16 a = (_Float16)o[r];
                oh4[r] = a; ol4[r] = (_Float16)(o[r] - (float)a);
            }
            const int cf = w * 16 + q * 4;
            *(half4*)&Obh[row & 1][row >> 1][cf] = oh4;
            *(half4*)&Obl[row & 1][row >> 1][cf] = ol4;
            if (row < n)
                *(f32x4*)(embs + (size_t)(p0 + row) * EMB + cf) = o;
        }
        __syncthreads();
    }
}

// ---------------------------------------------------------------------------
extern "C" void kernel_launch(void* const* d_in, const int* in_sizes, int n_in,
                              void* d_out, int out_size, void* d_ws, size_t ws_size,
                              hipStream_t stream)
{
    const float* lv = (const float*)d_in[0];
    const float* We = (const float*)d_in[1];
    const float* be = (const float*)d_in[2];
    const float* W1 = (const float*)d_in[3];
    const float* b1 = (const float*)d_in[4];
    const float* W2 = (const float*)d_in[5];
    const float* b2 = (const float*)d_in[6];
    float* embs = (float*)d_out;

    _Float16* W1f = (_Float16*)d_ws;            // 65536 f16 = 128 KB
    _Float16* W2f = W1f + 65536;                // 32768 f16 =  64 KB
    _Float16* W1l = W2f + 32768;                // 65536 f16 = 128 KB
    _Float16* W2l = W1l + 65536;                // 32768 f16 =  64 KB  (384 KB total)

    prep_weights<<<48, 256, 0, stream>>>(W1, W2, W1f, W2f, W1l, W2l);
    leaf_embed<<<N_LEAVES / 16, 256, 0, stream>>>(lv, We, be, embs);
    for (int l = DEPTH - 1; l >= 6; --l) {
        const int p0 = (1 << l) - 1, n = 1 << l;
        level_mfma<<<n / 64, 256, 0, stream>>>(W1f, W2f, b1, b2, embs, p0);
    }
    tail_levels<<<1, 512, 0, stream>>>(W1f, W1l, W2f, W2l, b1, b2, embs);
}